// Round 3
// baseline (154.784 us; speedup 1.0000x reference)
//
#include <hip/hip_runtime.h>
#include <stdint.h>

// Problem constants (from reference)
#define B_SZ   512
#define T_SZ   100
#define NPRE   256
#define NPOST  256
#define KTOT   (B_SZ * T_SZ)   // 51200

typedef __bf16 bf16x8 __attribute__((ext_vector_type(8)));
typedef float  floatx4 __attribute__((ext_vector_type(4)));

__device__ __forceinline__ uint32_t bf16_rne(float v) {
    uint32_t bits = __float_as_uint(v);
    return (bits + 0x7FFFu + ((bits >> 16) & 1u)) >> 16;
}
__device__ __forceinline__ uint32_t pack_trunc2(float a, float b) {
    return (__float_as_uint(a) >> 16) | (__float_as_uint(b) & 0xFFFF0000u);
}

// ---------------------------------------------------------------------------
// R14: row-contiguous wide loads + in-register transpose.
// Evidence (R10-R13): all pipes <12%, occupancy-insensitive, HBM 1.3-2.4 TB/s
// -> bound by ~2400-3600 scalar strided wave-VMEM instrs/CU (4-line splits),
// not by TLP. Fix: every global load is a contiguous row segment
// (float4/float2), transpose happens in-lane.
//
// 256 blocks x 1024 thr (16 waves, 1 block/CU). Block bx: batches 2bx,2bx+1,
// FULL 256p x 256q tile (inputs read exactly once). K chunked: 4 chunks of
// 32 t per batch -> 8 phases, A/B chunk buffers double-buffered (64 KB LDS).
//
// Roles: waves 0,1 = A-scan (lane owns p = w*128+2l, +1: float2 row loads;
// scan recurrence is lane-local, carries in regs, bit-identical fp32+RNE
// sequence); waves 2..5 = B-stage (wave 2+g handles t-oct g: 8 float4 row
// loads -> lane owns q=4l..4l+3 across 8 t -> pack 8 t per b128 write).
// All 16 waves MFMA: wave w owns 64p x 64q (16 frags, 64 AGPR).
//
// Phase k (k=0..7, batch=k>>2, chunk=k&3): stage chunk k+1 into buf[(k+1)&1]
// (loads issue first = T14), MFMA buf[k&1], one barrier. Pads (t>=100):
// B writes zeros (so A pad can be garbage), loads guarded.
//
// LDS line layout per chunk (proven R10 fragment form): X[line=n>>4]
// [slot = toct*16 + (n&15)][8 t] bf16; fragment read = b128 at [line][lane*8].
// ---------------------------------------------------------------------------
__global__ __launch_bounds__(1024, 4) void stdp_fused_gemm(
    const float* __restrict__ pre, const float* __restrict__ post,
    float* __restrict__ partial)
{
    __shared__ __align__(16) unsigned short A_lds[2][16][512];  // 32 KB
    __shared__ __align__(16) unsigned short B_lds[2][16][512];  // 32 KB

    const int bx   = blockIdx.x;                  // 0..255
    const int tid  = threadIdx.x;                 // 0..1023
    const int lane = tid & 63, wave = tid >> 6;   // wave 0..15
    const int l15 = lane & 15, l4 = lane >> 4;

    const float decay = 0.95122942450071400910f;  // expf(-1/20)
    const int b0 = 2 * bx;

    float c0 = 0.0f, c1 = 0.0f;                   // scan carries (waves 0,1)

    // A-scan geometry (waves 0,1)
    const int p0  = (wave & 1) * 128 + 2 * lane;  // valid when wave<2
    const int apg = p0 >> 4, ap15 = p0 & 15;
    // B-stage geometry (waves 2..5)
    const int bg  = wave - 2;                     // t-oct group 0..3
    const int qg  = lane >> 2, q15 = (4 * lane) & 15;

    floatx4 acc[4][4] = {};

    // ---- staging helpers (macros keep indices compile-time) ----
#define STAGE_A(BUF, BT, CK)                                                   \
    {                                                                          \
        const int b_ = b0 + (BT);                                              \
        if ((CK) == 0) { c0 = 0.0f; c1 = 0.0f; }                               \
        const float* rb_ = pre + (size_t)b_ * (T_SZ * NPRE) +                  \
                           (wave & 1) * 128 + 2 * lane;                        \
        _Pragma("unroll")                                                      \
        for (int og_ = 0; og_ < 4; ++og_) {                                    \
            float xx_[16];                                                     \
            _Pragma("unroll")                                                  \
            for (int j_ = 0; j_ < 8; ++j_) {                                   \
                const int t_ = (CK) * 32 + og_ * 8 + j_;                       \
                if (t_ < T_SZ) {                                               \
                    float2 v_ = *(const float2*)(rb_ + (size_t)t_ * NPRE);     \
                    xx_[2 * j_] = v_.x; xx_[2 * j_ + 1] = v_.y;                \
                } else { xx_[2 * j_] = 0.0f; xx_[2 * j_ + 1] = 0.0f; }         \
            }                                                                  \
            uint32_t u0_[4], u1_[4];                                           \
            _Pragma("unroll")                                                  \
            for (int m_ = 0; m_ < 4; ++m_) {                                   \
                uint32_t lo0_ = bf16_rne(c0);                                  \
                c0 = decay * (c0 + xx_[4 * m_ + 0]);                           \
                uint32_t lo1_ = bf16_rne(c1);                                  \
                c1 = decay * (c1 + xx_[4 * m_ + 1]);                           \
                uint32_t hi0_ = bf16_rne(c0);                                  \
                c0 = decay * (c0 + xx_[4 * m_ + 2]);                           \
                uint32_t hi1_ = bf16_rne(c1);                                  \
                c1 = decay * (c1 + xx_[4 * m_ + 3]);                           \
                u0_[m_] = lo0_ | (hi0_ << 16);                                 \
                u1_[m_] = lo1_ | (hi1_ << 16);                                 \
            }                                                                  \
            *(uint4*)&A_lds[BUF][apg][(og_ * 16 + ap15) * 8] =                 \
                make_uint4(u0_[0], u0_[1], u0_[2], u0_[3]);                    \
            *(uint4*)&A_lds[BUF][apg][(og_ * 16 + ap15 + 1) * 8] =             \
                make_uint4(u1_[0], u1_[1], u1_[2], u1_[3]);                    \
        }                                                                      \
    }

#define STAGE_B(BUF, BT, CK)                                                   \
    {                                                                          \
        const int b_ = b0 + (BT);                                              \
        const float* rb_ = post + (size_t)b_ * (T_SZ * NPOST) + 4 * lane;      \
        float xx_[8][4];                                                       \
        _Pragma("unroll")                                                      \
        for (int j_ = 0; j_ < 8; ++j_) {                                       \
            const int t_ = (CK) * 32 + bg * 8 + j_;                            \
            if (t_ < T_SZ) {                                                   \
                float4 v_ = *(const float4*)(rb_ + (size_t)t_ * NPOST);        \
                xx_[j_][0] = v_.x; xx_[j_][1] = v_.y;                          \
                xx_[j_][2] = v_.z; xx_[j_][3] = v_.w;                          \
            } else {                                                           \
                xx_[j_][0] = 0.0f; xx_[j_][1] = 0.0f;                          \
                xx_[j_][2] = 0.0f; xx_[j_][3] = 0.0f;                          \
            }                                                                  \
        }                                                                      \
        _Pragma("unroll")                                                      \
        for (int c_ = 0; c_ < 4; ++c_) {                                       \
            uint32_t u_[4];                                                    \
            _Pragma("unroll")                                                  \
            for (int m_ = 0; m_ < 4; ++m_)                                     \
                u_[m_] = pack_trunc2(xx_[2 * m_][c_], xx_[2 * m_ + 1][c_]);    \
            *(uint4*)&B_lds[BUF][qg][(bg * 16 + q15 + c_) * 8] =               \
                make_uint4(u_[0], u_[1], u_[2], u_[3]);                        \
        }                                                                      \
    }

#define MFMA_STEP(BUF)                                                         \
    {                                                                          \
        bf16x8 af_[4], bf_[4];                                                 \
        _Pragma("unroll")                                                      \
        for (int f_ = 0; f_ < 4; ++f_) {                                       \
            af_[f_] = *(const bf16x8*)&A_lds[BUF][(wave >> 2) * 4 + f_]        \
                                           [lane * 8];                         \
            bf_[f_] = *(const bf16x8*)&B_lds[BUF][(wave & 3) * 4 + f_]         \
                                           [lane * 8];                         \
        }                                                                      \
        _Pragma("unroll")                                                      \
        for (int fa_ = 0; fa_ < 4; ++fa_)                                      \
            _Pragma("unroll")                                                  \
            for (int fb_ = 0; fb_ < 4; ++fb_)                                  \
                acc[fa_][fb_] = __builtin_amdgcn_mfma_f32_16x16x32_bf16(       \
                    af_[fa_], bf_[fb_], acc[fa_][fb_], 0, 0, 0);               \
    }

    // ---- prologue: stage chunk 0 of batch 0 into buffer 0 ----
    if (wave < 2)      STAGE_A(0, 0, 0)
    else if (wave < 6) STAGE_B(0, 0, 0)
    __syncthreads();

    // ---- 8 pipelined phases (batch = k>>2, chunk = k&3) ----
#pragma unroll
    for (int k = 0; k < 8; ++k) {
        const int cur = k & 1, nxt = cur ^ 1;
        if (k < 7) {
            // loads for chunk k+1 issue first; pack+write consume them after
            // the compiler schedules the (independent) MFMA in between
            if (wave < 2)      STAGE_A(nxt, (k + 1) >> 2, (k + 1) & 3)
            else if (wave < 6) STAGE_B(nxt, (k + 1) >> 2, (k + 1) & 3)
        }
        MFMA_STEP(cur)
        __syncthreads();
    }

    // ---- writeout: partial[bx][p 256][q 256] ----
    // C/D layout (m89/m91): col = lane&15, row = (lane>>4)*4 + reg
    float* pout = partial + (size_t)bx * (256 * 256);
#pragma unroll
    for (int fa = 0; fa < 4; ++fa) {
        const int r0 = (wave >> 2) * 64 + fa * 16 + l4 * 4;
#pragma unroll
        for (int fb = 0; fb < 4; ++fb) {
            const int c = (wave & 3) * 64 + fb * 16 + l15;
#pragma unroll
            for (int v = 0; v < 4; ++v)
                pout[(size_t)(r0 + v) * 256 + c] = acc[fa][fb][v];
        }
    }
#undef STAGE_A
#undef STAGE_B
#undef MFMA_STEP
}

// ---------------------------------------------------------------------------
// Reduce stage 1: partial[256][65536] -> tmp[8][65536].
// 2048 blocks x 256 thr; thread t: g = t>>16, e = t&65535; sums blocks
// g*32..g*32+31 (4 independent chains). Coalesced (consecutive t -> e).
// ---------------------------------------------------------------------------
__global__ __launch_bounds__(256) void stdp_reduce1(
    const float* __restrict__ partial, float* __restrict__ tmp)
{
    const int t = blockIdx.x * 256 + threadIdx.x;  // 0..524287
    const int g = t >> 16;                         // 0..7
    const int e = t & 65535;
    const float* src = partial + ((size_t)g * 32) * 65536 + e;
    float a4[4] = {};
#pragma unroll
    for (int i = 0; i < 8; ++i)
#pragma unroll
        for (int u = 0; u < 4; ++u)
            a4[u] += src[(size_t)(i * 4 + u) * 65536];
    tmp[t] = (a4[0] + a4[1]) + (a4[2] + a4[3]);
}

// ---------------------------------------------------------------------------
// Reduce stage 2: 8 -> 1, scale by (A+ - A-)/(B*T). Plain layout (no tiling).
// ---------------------------------------------------------------------------
__global__ __launch_bounds__(256) void stdp_reduce2(
    const float* __restrict__ tmp, float* __restrict__ out)
{
    const int idx = blockIdx.x * 256 + threadIdx.x;  // 0..65535
    float a[4];
#pragma unroll
    for (int u = 0; u < 4; ++u)
        a[u] = tmp[(size_t)(2 * u) * 65536 + idx] +
               tmp[(size_t)(2 * u + 1) * 65536 + idx];
    const float scale = (0.005f - 0.00525f) * (1.0f / (float)KTOT);
    out[idx] = ((a[0] + a[1]) + (a[2] + a[3])) * scale;
}

// ---------------------------------------------------------------------------
extern "C" void kernel_launch(void* const* d_in, const int* in_sizes, int n_in,
                              void* d_out, int out_size, void* d_ws, size_t ws_size,
                              hipStream_t stream)
{
    const float* pre  = (const float*)d_in[0];   // [512,100,256]
    const float* post = (const float*)d_in[1];   // [512,100,256]
    float* out = (float*)d_out;                  // [256,256]

    // ws: partial 64 MB | tmp 2 MB
    float* partial = (float*)d_ws;
    float* tmp     = (float*)((char*)d_ws + (size_t)67108864);

    stdp_fused_gemm<<<256, 1024, 0, stream>>>(pre, post, partial);
    stdp_reduce1<<<2048, 256, 0, stream>>>(partial, tmp);
    stdp_reduce2<<<256, 256, 0, stream>>>(tmp, out);
}